// Round 2
// baseline (345.490 us; speedup 1.0000x reference)
//
#include <hip/hip_runtime.h>

typedef unsigned short u16;
typedef unsigned int u32;
typedef __bf16 bf16x8 __attribute__((ext_vector_type(8)));
typedef float f32x4 __attribute__((ext_vector_type(4)));

__device__ __forceinline__ u16 f2bf(float f) {
  union { float f; u32 u; } c; c.f = f;
  return (u16)((c.u + 0x7fffu + ((c.u >> 16) & 1u)) >> 16);  // RNE
}
__device__ __forceinline__ float2 upk2(u32 v) {
  union { u32 u; float f; } a, b; a.u = v << 16; b.u = v & 0xffff0000u;
  return make_float2(a.f, b.f);
}
__device__ __forceinline__ u32 pk2(float x, float y) {
  return (u32)f2bf(x) | ((u32)f2bf(y) << 16);
}

// ---------------- fp32 -> bf16 cast ----------------
__global__ __launch_bounds__(256) void k_cast(const float4* __restrict__ in,
                                              uint2* __restrict__ out, int n4) {
  int i = blockIdx.x * 256 + threadIdx.x;
  if (i < n4) {
    float4 v = in[i];
    out[i] = make_uint2(pk2(v.x, v.y), pk2(v.z, v.w));
  }
}

// ---------------- CSR build ----------------
__global__ __launch_bounds__(256) void k_hist(const int* __restrict__ dst,
                                              int* __restrict__ counts, int E) {
  int e = blockIdx.x * 256 + threadIdx.x;
  if (e < E) atomicAdd(&counts[dst[e]], 1);
}

__global__ __launch_bounds__(256) void k_scan1(const int* __restrict__ counts,
                                               int* __restrict__ excl,
                                               int* __restrict__ partials, int n) {
  __shared__ int sh[256];
  int b = blockIdx.x, t = threadIdx.x;
  int base = b * 1024 + t * 4;
  int v[4];
#pragma unroll
  for (int j = 0; j < 4; ++j) { int i = base + j; v[j] = (i < n) ? counts[i] : 0; }
  int tot = v[0] + v[1] + v[2] + v[3];
  sh[t] = tot; __syncthreads();
  for (int off = 1; off < 256; off <<= 1) {
    int x = (t >= off) ? sh[t - off] : 0;
    __syncthreads();
    sh[t] += x;
    __syncthreads();
  }
  int run = sh[t] - tot;  // exclusive over threads in block
#pragma unroll
  for (int j = 0; j < 4; ++j) {
    int i = base + j;
    if (i < n) excl[i] = run;
    run += v[j];
  }
  if (t == 255) partials[b] = sh[255];
}

__global__ __launch_bounds__(128) void k_scan2(int* __restrict__ partials, int nb) {
  __shared__ int sh[128];
  int t = threadIdx.x;
  int v = (t < nb) ? partials[t] : 0;
  sh[t] = v; __syncthreads();
  for (int off = 1; off < 128; off <<= 1) {
    int x = (t >= off) ? sh[t - off] : 0;
    __syncthreads();
    sh[t] += x;
    __syncthreads();
  }
  if (t < nb) partials[t] = sh[t] - v;  // exclusive
}

__global__ __launch_bounds__(256) void k_scan3(int* __restrict__ rowstart,
                                               int* __restrict__ cursor,
                                               const int* __restrict__ partials,
                                               int n, int E) {
  int i = blockIdx.x * 256 + threadIdx.x;
  if (i < n) {
    int v = rowstart[i] + partials[i >> 10];
    rowstart[i] = v;
    cursor[i] = v;
  }
  if (i == 0) rowstart[n] = E;
}

__global__ __launch_bounds__(256) void k_fill(const int* __restrict__ src,
                                              const int* __restrict__ dst,
                                              int* __restrict__ cursor,
                                              int* __restrict__ edge_src, int E) {
  int e = blockIdx.x * 256 + threadIdx.x;
  if (e < E) {
    int d = dst[e];
    int pos = atomicAdd(&cursor[d], 1);
    edge_src[pos] = src[e];
  }
}

// ---------------- weight transpose+cast: wT[w][n][k] = bf16(w[k][n]) ----------------
__global__ __launch_bounds__(256) void k_tr(const float* __restrict__ w0,
                                            const float* __restrict__ w1,
                                            const float* __restrict__ w2,
                                            const float* __restrict__ w3,
                                            u16* __restrict__ wT) {
  int id = blockIdx.x * 256 + threadIdx.x;  // 0..65535
  int w = id >> 14, rem = id & 16383;
  int nn = rem >> 7, kk = rem & 127;
  const float* s = (w == 0) ? w0 : (w == 1) ? w1 : (w == 2) ? w2 : w3;
  wT[id] = f2bf(s[kk * 128 + nn]);
}

// ---------------- aggregation: out[n] = in[n] + sum_{s in nbr(n)} in[s] (bf16 io, f32 acc) --------
__global__ __launch_bounds__(256) void k_agg(const u32* __restrict__ in,
                                             u32* __restrict__ out,
                                             const int* __restrict__ rowstart,
                                             const int* __restrict__ edge_src, int N) {
  int node = blockIdx.x * 4 + (threadIdx.x >> 6);
  int lane = threadIdx.x & 63;
  if (node >= N) return;
  float2 acc = upk2(in[node * 64 + lane]);
  int e0 = rowstart[node], e1 = rowstart[node + 1];
  for (int e = e0; e < e1; ++e) {
    int s = edge_src[e];
    float2 v = upk2(in[s * 64 + lane]);
    acc.x += v.x; acc.y += v.y;
  }
  out[node * 64 + lane] = pk2(acc.x, acc.y);
}

// ---------------- fused MLP: out = relu(in@wA+bA)@wB + bB  (+ optional head dot) ----------------
// LDS layout: 16B chunks, chunk c of row r stored at r*128 + ((c ^ (r&15))*8)
template <bool HEAD>
__global__ __launch_bounds__(256) void k_mlp(const u16* __restrict__ in,   // [N,128] bf16
                                             const u16* __restrict__ wAT,  // [128n][128k] bf16
                                             const float* __restrict__ bA,
                                             const u16* __restrict__ wBT,
                                             const float* __restrict__ bB,
                                             const float* __restrict__ wo,  // [128] (HEAD)
                                             const float* __restrict__ bo,  // [1]   (HEAD)
                                             void* __restrict__ outp, int N) {
  __shared__ u16 lA[64 * 128];    // A tile / h1 tile / out tile (rows are wave-private)
  __shared__ u16 lW[128 * 128];   // weight tile (transposed: row n, k contiguous)
  const int tid = threadIdx.x;
  const int wave = tid >> 6, lane = tid & 63;
  const int base = blockIdx.x * 64;

  // stage A tile (64 rows x 128 bf16), swizzled
#pragma unroll
  for (int it = 0; it < 4; ++it) {
    int id = it * 256 + tid;            // 1024 chunks
    int row = id >> 4, c = id & 15;
    uint4 v = make_uint4(0u, 0u, 0u, 0u);
    if (base + row < N) v = *(const uint4*)&in[(base + row) * 128 + c * 8];
    *(uint4*)&lA[row * 128 + ((c ^ (row & 15)) << 3)] = v;
  }
  // stage W = wAT (128 rows x 128)
#pragma unroll
  for (int it = 0; it < 8; ++it) {
    int id = it * 256 + tid;            // 2048 chunks
    int row = id >> 4, c = id & 15;
    uint4 v = *(const uint4*)&wAT[row * 128 + c * 8];
    *(uint4*)&lW[row * 128 + ((c ^ (row & 15)) << 3)] = v;
  }
  __syncthreads();

  const int m16 = lane & 15, quad = lane >> 4;
  const int mrow = wave * 16 + m16;

  // ---- GEMM1: h1 = relu(A @ wA + bA) ----
  bf16x8 aF[4];
#pragma unroll
  for (int ks = 0; ks < 4; ++ks)
    aF[ks] = *(const bf16x8*)&lA[mrow * 128 + (((ks * 4 + quad) ^ m16) << 3)];
  f32x4 acc[8];
#pragma unroll
  for (int t = 0; t < 8; ++t) acc[t] = (f32x4){0.f, 0.f, 0.f, 0.f};
#pragma unroll
  for (int t = 0; t < 8; ++t) {
    int nrow = t * 16 + m16;
#pragma unroll
    for (int ks = 0; ks < 4; ++ks) {
      bf16x8 bF = *(const bf16x8*)&lW[nrow * 128 + (((ks * 4 + quad) ^ m16) << 3)];
      acc[t] = __builtin_amdgcn_mfma_f32_16x16x32_bf16(aF[ks], bF, acc[t], 0, 0, 0);
    }
  }
  __syncthreads();  // all GEMM1 LDS reads complete before overwriting lA/lW

  // epilogue 1: write h1 (bf16) into lA (own wave's rows only)
#pragma unroll
  for (int t = 0; t < 8; ++t) {
    int n = t * 16 + m16;
    float bias = bA[n];
#pragma unroll
    for (int r = 0; r < 4; ++r) {
      int rloc = quad * 4 + r;                 // row within wave's 16 (== absrow & 15)
      int absrow = wave * 16 + rloc;
      float v = acc[t][r] + bias;
      v = v > 0.f ? v : 0.f;
      lA[absrow * 128 + ((((n >> 3) ^ rloc) << 3) | (n & 7))] = f2bf(v);
    }
  }
  // restage W = wBT
#pragma unroll
  for (int it = 0; it < 8; ++it) {
    int id = it * 256 + tid;
    int row = id >> 4, c = id & 15;
    uint4 v = *(const uint4*)&wBT[row * 128 + c * 8];
    *(uint4*)&lW[row * 128 + ((c ^ (row & 15)) << 3)] = v;
  }
  __syncthreads();

  // ---- GEMM2: h2 = h1 @ wB + bB ----
#pragma unroll
  for (int ks = 0; ks < 4; ++ks)
    aF[ks] = *(const bf16x8*)&lA[mrow * 128 + (((ks * 4 + quad) ^ m16) << 3)];
#pragma unroll
  for (int t = 0; t < 8; ++t) acc[t] = (f32x4){0.f, 0.f, 0.f, 0.f};
#pragma unroll
  for (int t = 0; t < 8; ++t) {
    int nrow = t * 16 + m16;
#pragma unroll
    for (int ks = 0; ks < 4; ++ks) {
      bf16x8 bF = *(const bf16x8*)&lW[nrow * 128 + (((ks * 4 + quad) ^ m16) << 3)];
      acc[t] = __builtin_amdgcn_mfma_f32_16x16x32_bf16(aF[ks], bF, acc[t], 0, 0, 0);
    }
  }
  // epilogue 2: write result (bf16) into lA (own rows; own aF already consumed)
#pragma unroll
  for (int t = 0; t < 8; ++t) {
    int n = t * 16 + m16;
    float bias = bB[n];
#pragma unroll
    for (int r = 0; r < 4; ++r) {
      int rloc = quad * 4 + r;
      int absrow = wave * 16 + rloc;
      float v = acc[t][r] + bias;
      lA[absrow * 128 + ((((n >> 3) ^ rloc) << 3) | (n & 7))] = f2bf(v);
    }
  }
  __syncthreads();  // cross-wave readback below

  if (!HEAD) {
    u16* out = (u16*)outp;
    // coalesced tile store: 64 rows x 256B
#pragma unroll
    for (int it = 0; it < 4; ++it) {
      int id = it * 256 + tid;
      int row = id >> 4, c = id & 15;
      if (base + row < N) {
        uint4 v = *(const uint4*)&lA[row * 128 + ((c ^ (row & 15)) << 3)];
        *(uint4*)&out[(base + row) * 128 + c * 8] = v;
      }
    }
  } else {
    float* out = (float*)outp;
    // head: out[row] = h2b[row,:] . wo + bo ; 4 threads per row
    int row = tid >> 2, qh = tid & 3;
    float s = 0.f;
#pragma unroll
    for (int j = 0; j < 4; ++j) {
      int c = qh * 4 + j;
      uint4 v = *(const uint4*)&lA[row * 128 + ((c ^ (row & 15)) << 3)];
      const float* w = &wo[c * 8];
      float2 p;
      p = upk2(v.x); s += p.x * w[0] + p.y * w[1];
      p = upk2(v.y); s += p.x * w[2] + p.y * w[3];
      p = upk2(v.z); s += p.x * w[4] + p.y * w[5];
      p = upk2(v.w); s += p.x * w[6] + p.y * w[7];
    }
    s += __shfl_xor(s, 1, 64);
    s += __shfl_xor(s, 2, 64);
    if (qh == 0 && base + row < N) {
      out[base + row] = s + bo[0];
    }
  }
}

extern "C" void kernel_launch(void* const* d_in, const int* in_sizes, int n_in,
                              void* d_out, int out_size, void* d_ws, size_t ws_size,
                              hipStream_t stream) {
  const float* x = (const float*)d_in[0];
  const int* ei = (const int*)d_in[1];
  const int E = in_sizes[1] / 2;
  const int N = in_sizes[0] / 128;
  const int* srcI = ei;
  const int* dstI = ei + E;
  const float* w1a = (const float*)d_in[2];
  const float* b1a = (const float*)d_in[3];
  const float* w1b = (const float*)d_in[4];
  const float* b1b = (const float*)d_in[5];
  const float* w2a = (const float*)d_in[6];
  const float* b2a = (const float*)d_in[7];
  const float* w2b = (const float*)d_in[8];
  const float* b2b = (const float*)d_in[9];
  const float* wo = (const float*)d_in[10];
  const float* bo = (const float*)d_in[11];

  char* ws = (char*)d_ws;
  size_t off = 0;
  auto nx = [&](size_t bytes) {
    size_t o = off;
    off += (bytes + 511) & ~(size_t)511;
    return o;
  };
  int* cursor   = (int*)(ws + nx((size_t)N * 4));        // counts, then fill cursor
  int* rowstart = (int*)(ws + nx((size_t)(N + 1) * 4));
  int* partials = (int*)(ws + nx(4096));
  int* edge_src = (int*)(ws + nx((size_t)E * 4));
  u16* wT       = (u16*)(ws + nx((size_t)4 * 16384 * 2));
  u16* xb       = (u16*)(ws + nx((size_t)N * 128 * 2));  // bf16 x; later reused for agg2 out
  u16* bufA     = (u16*)(ws + nx((size_t)N * 128 * 2));  // agg1 out
  u16* bufB     = (u16*)(ws + nx((size_t)N * 128 * 2));  // mlp1 out (h1b)

  const int nb = (N + 1023) >> 10;  // scan chunks

  hipMemsetAsync(cursor, 0, (size_t)N * 4, stream);
  k_hist<<<(E + 255) / 256, 256, 0, stream>>>(dstI, cursor, E);
  k_scan1<<<nb, 256, 0, stream>>>(cursor, rowstart, partials, N);
  k_scan2<<<1, 128, 0, stream>>>(partials, nb);
  k_scan3<<<(N + 255) / 256, 256, 0, stream>>>(rowstart, cursor, partials, N, E);
  k_fill<<<(E + 255) / 256, 256, 0, stream>>>(srcI, dstI, cursor, edge_src, E);
  k_tr<<<256, 256, 0, stream>>>(w1a, w1b, w2a, w2b, wT);

  const int n4 = N * 32;  // N*128/4
  k_cast<<<(n4 + 255) / 256, 256, 0, stream>>>((const float4*)x, (uint2*)xb, n4);

  k_agg<<<(N + 3) / 4, 256, 0, stream>>>((const u32*)xb, (u32*)bufA, rowstart, edge_src, N);
  k_mlp<false><<<(N + 63) / 64, 256, 0, stream>>>(bufA, wT, b1a, wT + 16384, b1b,
                                                  nullptr, nullptr, bufB, N);
  k_agg<<<(N + 3) / 4, 256, 0, stream>>>((const u32*)bufB, (u32*)xb, rowstart, edge_src, N);
  k_mlp<true><<<(N + 63) / 64, 256, 0, stream>>>(xb, wT + 32768, b2a, wT + 49152, b2b,
                                                 wo, bo, d_out, N);
}

// Round 3
// 276.300 us; speedup vs baseline: 1.2504x; 1.2504x over previous
//
#include <hip/hip_runtime.h>

typedef unsigned short u16;
typedef unsigned int u32;
typedef __bf16 bf16x8 __attribute__((ext_vector_type(8)));
typedef float f32x4 __attribute__((ext_vector_type(4)));

__device__ __forceinline__ u16 f2bf(float f) {
  union { float f; u32 u; } c; c.f = f;
  return (u16)((c.u + 0x7fffu + ((c.u >> 16) & 1u)) >> 16);  // RNE
}
__device__ __forceinline__ float2 upk2(u32 v) {
  union { u32 u; float f; } a, b; a.u = v << 16; b.u = v & 0xffff0000u;
  return make_float2(a.f, b.f);
}
__device__ __forceinline__ u32 pk2(float x, float y) {
  return (u32)f2bf(x) | ((u32)f2bf(y) << 16);
}

// ---------------- fp32 -> bf16 cast ----------------
__global__ __launch_bounds__(256) void k_cast(const float4* __restrict__ in,
                                              uint2* __restrict__ out, int n4) {
  int i = blockIdx.x * 256 + threadIdx.x;
  if (i < n4) {
    float4 v = in[i];
    out[i] = make_uint2(pk2(v.x, v.y), pk2(v.z, v.w));
  }
}

// ---------------- CSR build ----------------
__global__ __launch_bounds__(256) void k_hist(const int* __restrict__ dst,
                                              int* __restrict__ counts, int E) {
  int e = blockIdx.x * 256 + threadIdx.x;
  if (e < E) atomicAdd(&counts[dst[e]], 1);
}

__global__ __launch_bounds__(256) void k_scan1(const int* __restrict__ counts,
                                               int* __restrict__ excl,
                                               int* __restrict__ partials, int n) {
  __shared__ int sh[256];
  int b = blockIdx.x, t = threadIdx.x;
  int base = b * 1024 + t * 4;
  int v[4];
#pragma unroll
  for (int j = 0; j < 4; ++j) { int i = base + j; v[j] = (i < n) ? counts[i] : 0; }
  int tot = v[0] + v[1] + v[2] + v[3];
  sh[t] = tot; __syncthreads();
  for (int off = 1; off < 256; off <<= 1) {
    int x = (t >= off) ? sh[t - off] : 0;
    __syncthreads();
    sh[t] += x;
    __syncthreads();
  }
  int run = sh[t] - tot;  // exclusive over threads in block
#pragma unroll
  for (int j = 0; j < 4; ++j) {
    int i = base + j;
    if (i < n) excl[i] = run;
    run += v[j];
  }
  if (t == 255) partials[b] = sh[255];
}

__global__ __launch_bounds__(128) void k_scan2(int* __restrict__ partials, int nb) {
  __shared__ int sh[128];
  int t = threadIdx.x;
  int v = (t < nb) ? partials[t] : 0;
  sh[t] = v; __syncthreads();
  for (int off = 1; off < 128; off <<= 1) {
    int x = (t >= off) ? sh[t - off] : 0;
    __syncthreads();
    sh[t] += x;
    __syncthreads();
  }
  if (t < nb) partials[t] = sh[t] - v;  // exclusive
}

__global__ __launch_bounds__(256) void k_scan3(int* __restrict__ rowstart,
                                               int* __restrict__ cursor,
                                               const int* __restrict__ partials,
                                               int n, int E) {
  int i = blockIdx.x * 256 + threadIdx.x;
  if (i < n) {
    int v = rowstart[i] + partials[i >> 10];
    rowstart[i] = v;
    cursor[i] = v;
  }
  if (i == 0) rowstart[n] = E;
}

__global__ __launch_bounds__(256) void k_fill(const int* __restrict__ src,
                                              const int* __restrict__ dst,
                                              int* __restrict__ cursor,
                                              int* __restrict__ edge_src, int E) {
  int e = blockIdx.x * 256 + threadIdx.x;
  if (e < E) {
    int d = dst[e];
    int pos = atomicAdd(&cursor[d], 1);
    edge_src[pos] = src[e];
  }
}

// ---------------- weight transpose+cast: wT[w][n][k] = bf16(w[k][n]) ----------------
__global__ __launch_bounds__(256) void k_tr(const float* __restrict__ w0,
                                            const float* __restrict__ w1,
                                            const float* __restrict__ w2,
                                            const float* __restrict__ w3,
                                            u16* __restrict__ wT) {
  int id = blockIdx.x * 256 + threadIdx.x;  // 0..65535
  int w = id >> 14, rem = id & 16383;
  int nn = rem >> 7, kk = rem & 127;
  const float* s = (w == 0) ? w0 : (w == 1) ? w1 : (w == 2) ? w2 : w3;
  wT[id] = f2bf(s[kk * 128 + nn]);
}

// ---------------- aggregation: out[n] = in[n] + sum_{s in nbr(n)} in[s] (bf16 io, f32 acc) --------
// One wave per node; node made wave-uniform via readfirstlane so edge indices
// become s_loads and row gathers become saddr-form global_load_dword.
// Edges processed in groups of 8 (clamped idx + 0/1 weight for tail) -> 8
// independent vmem loads in flight per wave instead of 1 (latency-bound fix).
__global__ __launch_bounds__(256) void k_agg(const u32* __restrict__ in,
                                             u32* __restrict__ out,
                                             const int* __restrict__ rowstart,
                                             const int* __restrict__ edge_src, int N) {
  int node = __builtin_amdgcn_readfirstlane(blockIdx.x * 4 + (threadIdx.x >> 6));
  int lane = threadIdx.x & 63;
  if (node >= N) return;
  const u32* __restrict__ col = in + lane;
  float2 acc = upk2(col[node * 64]);
  int e0 = rowstart[node], e1 = rowstart[node + 1];
  for (int e = e0; e < e1; e += 8) {
    int idx[8]; float w[8]; u32 v[8];
#pragma unroll
    for (int j = 0; j < 8; ++j) {
      int ej = e + j;
      int c = (ej < e1) ? ej : (e1 - 1);
      idx[j] = edge_src[c];
      w[j] = (ej < e1) ? 1.f : 0.f;
    }
#pragma unroll
    for (int j = 0; j < 8; ++j) v[j] = col[idx[j] * 64];
#pragma unroll
    for (int j = 0; j < 8; ++j) {
      float2 p = upk2(v[j]);
      acc.x = fmaf(w[j], p.x, acc.x);
      acc.y = fmaf(w[j], p.y, acc.y);
    }
  }
  out[node * 64 + lane] = pk2(acc.x, acc.y);
}

// ---------------- fused MLP: out = relu(in@wA+bA)@wB + bB  (+ optional head dot) ----------------
// LDS layout: 16B chunks, chunk c of row r stored at r*128 + ((c ^ (r&15))*8)
template <bool HEAD>
__global__ __launch_bounds__(256) void k_mlp(const u16* __restrict__ in,   // [N,128] bf16
                                             const u16* __restrict__ wAT,  // [128n][128k] bf16
                                             const float* __restrict__ bA,
                                             const u16* __restrict__ wBT,
                                             const float* __restrict__ bB,
                                             const float* __restrict__ wo,  // [128] (HEAD)
                                             const float* __restrict__ bo,  // [1]   (HEAD)
                                             void* __restrict__ outp, int N) {
  __shared__ u16 lA[64 * 128];    // A tile / h1 tile / out tile (rows are wave-private)
  __shared__ u16 lW[128 * 128];   // weight tile (transposed: row n, k contiguous)
  const int tid = threadIdx.x;
  const int wave = tid >> 6, lane = tid & 63;
  const int base = blockIdx.x * 64;

  // stage A tile (64 rows x 128 bf16), swizzled
#pragma unroll
  for (int it = 0; it < 4; ++it) {
    int id = it * 256 + tid;            // 1024 chunks
    int row = id >> 4, c = id & 15;
    uint4 v = make_uint4(0u, 0u, 0u, 0u);
    if (base + row < N) v = *(const uint4*)&in[(base + row) * 128 + c * 8];
    *(uint4*)&lA[row * 128 + ((c ^ (row & 15)) << 3)] = v;
  }
  // stage W = wAT (128 rows x 128)
#pragma unroll
  for (int it = 0; it < 8; ++it) {
    int id = it * 256 + tid;            // 2048 chunks
    int row = id >> 4, c = id & 15;
    uint4 v = *(const uint4*)&wAT[row * 128 + c * 8];
    *(uint4*)&lW[row * 128 + ((c ^ (row & 15)) << 3)] = v;
  }
  __syncthreads();

  const int m16 = lane & 15, quad = lane >> 4;
  const int mrow = wave * 16 + m16;

  // ---- GEMM1: h1 = relu(A @ wA + bA) ----
  bf16x8 aF[4];
#pragma unroll
  for (int ks = 0; ks < 4; ++ks)
    aF[ks] = *(const bf16x8*)&lA[mrow * 128 + (((ks * 4 + quad) ^ m16) << 3)];
  f32x4 acc[8];
#pragma unroll
  for (int t = 0; t < 8; ++t) acc[t] = (f32x4){0.f, 0.f, 0.f, 0.f};
#pragma unroll
  for (int t = 0; t < 8; ++t) {
    int nrow = t * 16 + m16;
#pragma unroll
    for (int ks = 0; ks < 4; ++ks) {
      bf16x8 bF = *(const bf16x8*)&lW[nrow * 128 + (((ks * 4 + quad) ^ m16) << 3)];
      acc[t] = __builtin_amdgcn_mfma_f32_16x16x32_bf16(aF[ks], bF, acc[t], 0, 0, 0);
    }
  }
  __syncthreads();  // all GEMM1 LDS reads complete before overwriting lA/lW

  // epilogue 1: write h1 (bf16) into lA (own wave's rows only)
#pragma unroll
  for (int t = 0; t < 8; ++t) {
    int n = t * 16 + m16;
    float bias = bA[n];
#pragma unroll
    for (int r = 0; r < 4; ++r) {
      int rloc = quad * 4 + r;                 // row within wave's 16 (== absrow & 15)
      int absrow = wave * 16 + rloc;
      float v = acc[t][r] + bias;
      v = v > 0.f ? v : 0.f;
      lA[absrow * 128 + ((((n >> 3) ^ rloc) << 3) | (n & 7))] = f2bf(v);
    }
  }
  // restage W = wBT
#pragma unroll
  for (int it = 0; it < 8; ++it) {
    int id = it * 256 + tid;
    int row = id >> 4, c = id & 15;
    uint4 v = *(const uint4*)&wBT[row * 128 + c * 8];
    *(uint4*)&lW[row * 128 + ((c ^ (row & 15)) << 3)] = v;
  }
  __syncthreads();

  // ---- GEMM2: h2 = h1 @ wB + bB ----
#pragma unroll
  for (int ks = 0; ks < 4; ++ks)
    aF[ks] = *(const bf16x8*)&lA[mrow * 128 + (((ks * 4 + quad) ^ m16) << 3)];
#pragma unroll
  for (int t = 0; t < 8; ++t) acc[t] = (f32x4){0.f, 0.f, 0.f, 0.f};
#pragma unroll
  for (int t = 0; t < 8; ++t) {
    int nrow = t * 16 + m16;
#pragma unroll
    for (int ks = 0; ks < 4; ++ks) {
      bf16x8 bF = *(const bf16x8*)&lW[nrow * 128 + (((ks * 4 + quad) ^ m16) << 3)];
      acc[t] = __builtin_amdgcn_mfma_f32_16x16x32_bf16(aF[ks], bF, acc[t], 0, 0, 0);
    }
  }
  // epilogue 2: write result (bf16) into lA (own rows; own aF already consumed)
#pragma unroll
  for (int t = 0; t < 8; ++t) {
    int n = t * 16 + m16;
    float bias = bB[n];
#pragma unroll
    for (int r = 0; r < 4; ++r) {
      int rloc = quad * 4 + r;
      int absrow = wave * 16 + rloc;
      float v = acc[t][r] + bias;
      lA[absrow * 128 + ((((n >> 3) ^ rloc) << 3) | (n & 7))] = f2bf(v);
    }
  }
  __syncthreads();  // cross-wave readback below

  if (!HEAD) {
    u16* out = (u16*)outp;
    // coalesced tile store: 64 rows x 256B
#pragma unroll
    for (int it = 0; it < 4; ++it) {
      int id = it * 256 + tid;
      int row = id >> 4, c = id & 15;
      if (base + row < N) {
        uint4 v = *(const uint4*)&lA[row * 128 + ((c ^ (row & 15)) << 3)];
        *(uint4*)&out[(base + row) * 128 + c * 8] = v;
      }
    }
  } else {
    float* out = (float*)outp;
    // head: out[row] = h2b[row,:] . wo + bo ; 4 threads per row
    int row = tid >> 2, qh = tid & 3;
    float s = 0.f;
#pragma unroll
    for (int j = 0; j < 4; ++j) {
      int c = qh * 4 + j;
      uint4 v = *(const uint4*)&lA[row * 128 + ((c ^ (row & 15)) << 3)];
      const float* w = &wo[c * 8];
      float2 p;
      p = upk2(v.x); s += p.x * w[0] + p.y * w[1];
      p = upk2(v.y); s += p.x * w[2] + p.y * w[3];
      p = upk2(v.z); s += p.x * w[4] + p.y * w[5];
      p = upk2(v.w); s += p.x * w[6] + p.y * w[7];
    }
    s += __shfl_xor(s, 1, 64);
    s += __shfl_xor(s, 2, 64);
    if (qh == 0 && base + row < N) {
      out[base + row] = s + bo[0];
    }
  }
}

extern "C" void kernel_launch(void* const* d_in, const int* in_sizes, int n_in,
                              void* d_out, int out_size, void* d_ws, size_t ws_size,
                              hipStream_t stream) {
  const float* x = (const float*)d_in[0];
  const int* ei = (const int*)d_in[1];
  const int E = in_sizes[1] / 2;
  const int N = in_sizes[0] / 128;
  const int* srcI = ei;
  const int* dstI = ei + E;
  const float* w1a = (const float*)d_in[2];
  const float* b1a = (const float*)d_in[3];
  const float* w1b = (const float*)d_in[4];
  const float* b1b = (const float*)d_in[5];
  const float* w2a = (const float*)d_in[6];
  const float* b2a = (const float*)d_in[7];
  const float* w2b = (const float*)d_in[8];
  const float* b2b = (const float*)d_in[9];
  const float* wo = (const float*)d_in[10];
  const float* bo = (const float*)d_in[11];

  char* ws = (char*)d_ws;
  size_t off = 0;
  auto nx = [&](size_t bytes) {
    size_t o = off;
    off += (bytes + 511) & ~(size_t)511;
    return o;
  };
  int* cursor   = (int*)(ws + nx((size_t)N * 4));        // counts, then fill cursor
  int* rowstart = (int*)(ws + nx((size_t)(N + 1) * 4));
  int* partials = (int*)(ws + nx(4096));
  int* edge_src = (int*)(ws + nx((size_t)E * 4));
  u16* wT       = (u16*)(ws + nx((size_t)4 * 16384 * 2));
  u16* xb       = (u16*)(ws + nx((size_t)N * 128 * 2));  // bf16 x; later reused for agg2 out
  u16* bufA     = (u16*)(ws + nx((size_t)N * 128 * 2));  // agg1 out
  u16* bufB     = (u16*)(ws + nx((size_t)N * 128 * 2));  // mlp1 out (h1b)

  const int nb = (N + 1023) >> 10;  // scan chunks

  hipMemsetAsync(cursor, 0, (size_t)N * 4, stream);
  k_hist<<<(E + 255) / 256, 256, 0, stream>>>(dstI, cursor, E);
  k_scan1<<<nb, 256, 0, stream>>>(cursor, rowstart, partials, N);
  k_scan2<<<1, 128, 0, stream>>>(partials, nb);
  k_scan3<<<(N + 255) / 256, 256, 0, stream>>>(rowstart, cursor, partials, N, E);
  k_fill<<<(E + 255) / 256, 256, 0, stream>>>(srcI, dstI, cursor, edge_src, E);
  k_tr<<<256, 256, 0, stream>>>(w1a, w1b, w2a, w2b, wT);

  const int n4 = N * 32;  // N*128/4
  k_cast<<<(n4 + 255) / 256, 256, 0, stream>>>((const float4*)x, (uint2*)xb, n4);

  k_agg<<<(N + 3) / 4, 256, 0, stream>>>((const u32*)xb, (u32*)bufA, rowstart, edge_src, N);
  k_mlp<false><<<(N + 63) / 64, 256, 0, stream>>>(bufA, wT, b1a, wT + 16384, b1b,
                                                  nullptr, nullptr, bufB, N);
  k_agg<<<(N + 3) / 4, 256, 0, stream>>>((const u32*)bufB, (u32*)xb, rowstart, edge_src, N);
  k_mlp<true><<<(N + 63) / 64, 256, 0, stream>>>(xb, wT + 32768, b2a, wT + 49152, b2b,
                                                 wo, bo, d_out, N);
}